// Round 6
// baseline (247.380 us; speedup 1.0000x reference)
//
#include <hip/hip_runtime.h>
#include <hip/hip_bf16.h>

// ROI Align (FPN, PH=PW=7, SR=2), fp32 I/O (verified R4).
// R6: the kernel is transaction-bound (R5 post-mortem: divergent wave-gathers
// cost ~1 L1 line-transaction per lane; raising per-thread ILP did nothing).
// Fix: stage each (roi, channel) feature rect into LDS with COALESCED
// row-major loads, then do the 16-gather bilinear math from LDS.
//   block = (roi k, 16-channel group); 4 chunks of CB=4 channels.
//   Region rect <= 60x60 floats (max box 232px * 0.25 + 2). LDS 57.6 KB.
//   Sample geometry computed once per thread, reused for all 4 chunks.

#define NUM_CH 256
#define CB     4              // channels staged per chunk
#define GRP    16             // channels per block
#define NCHUNK (GRP / CB)
#define MAXR   60
#define MAXE   (MAXR * MAXR)  // 3600 floats per staged channel

__global__ __launch_bounds__(256) void roi_align_lds_kernel(
    const float* __restrict__ f0,
    const float* __restrict__ f1,
    const float* __restrict__ f2,
    const float* __restrict__ f3,
    const float* __restrict__ rois_f,
    const int* __restrict__ level,
    float* __restrict__ out)
{
    __shared__ float lds[CB * MAXE];   // 57,600 B

    const int tid = threadIdx.x;
    const int k   = blockIdx.x >> 4;   // ROI
    const int g   = blockIdx.x & 15;   // channel group (16 ch)

    // ---- per-ROI scalars (all threads; rois reads are wave-broadcast) ----
    int lvl = level[k];
    const float* f;
    int H, W; float scale;
    if (lvl == 0)      { f = f0; H = 200; W = 200; scale = 0.25f;    }
    else if (lvl == 1) { f = f1; H = 100; W = 100; scale = 0.125f;   }
    else if (lvl == 2) { f = f2; H = 50;  W = 50;  scale = 0.0625f;  }
    else               { f = f3; H = 25;  W = 25;  scale = 0.03125f; }

    const float* rf = rois_f + (size_t)k * 5;
    float r0 = rf[0];
    float x1 = rf[1] * scale, y1 = rf[2] * scale;
    float x2 = rf[3] * scale, y2 = rf[4] * scale;
    int b = (int)r0;
    b = (b < 0) ? 0 : ((b > 1) ? 1 : b);

    float bin_h = fmaxf(y2 - y1, 1.0f) * (1.0f / 7.0f);
    float bin_w = fmaxf(x2 - x1, 1.0f) * (1.0f / 7.0f);

    // ---- staged region rect: [row_lo..row_hi] x [col_lo..col_hi] ----------
    // sample coords are monotone: first = o + 0.25*bin, last = o + 6.75*bin
    float ys0 = y1 + 0.25f * bin_h, ysl = y1 + 6.75f * bin_h;
    float xs0 = x1 + 0.25f * bin_w, xsl = x1 + 6.75f * bin_w;
    int row_lo = min((int)fmaxf(ys0, 0.0f), H - 1);
    int row_hi = min(min((int)fmaxf(ysl, 0.0f), H - 1) + 1, H - 1);
    int col_lo = min((int)fmaxf(xs0, 0.0f), W - 1);
    int col_hi = min(min((int)fmaxf(xsl, 0.0f), W - 1) + 1, W - 1);
    int rows = row_hi - row_lo + 1;
    int cols = col_hi - col_lo + 1;
    rows = max(1, min(rows, MAXR));   // provably <= 60; defensive
    cols = max(1, min(cols, MAXR));
    const int F = rows * cols;
    const float rcp_cols = 1.0f / (float)cols;

    // ---- per-thread sample geometry (channel-independent; reused 4x) ------
    const bool active = tid < CB * 49;       // 196 compute lanes
    int   soff[4][4];                        // [sample][corner] lds offsets
    float swt [4][4];                        // corner weights * valid * 0.25
    int ci = 0, p = 0;
    if (active) {
        ci = tid / 49;
        p  = tid - ci * 49;
        int ph = p / 7;
        int pw = p - ph * 7;
        #pragma unroll
        for (int s = 0; s < 4; ++s) {
            int sy = s >> 1, sx = s & 1;
            float y = y1 + (float)ph * bin_h + ((float)sy + 0.5f) * (bin_h * 0.5f);
            float x = x1 + (float)pw * bin_w + ((float)sx + 0.5f) * (bin_w * 0.5f);
            bool valid = (y > -1.0f) && (y < (float)H) && (x > -1.0f) && (x < (float)W);
            float yc = fmaxf(y, 0.0f), xc = fmaxf(x, 0.0f);
            int yl = min((int)yc, H - 1), yh = min(yl + 1, H - 1);
            int xl = min((int)xc, W - 1), xh = min(xl + 1, W - 1);
            float ly = (yl >= H - 1) ? 0.0f : (yc - (float)yl);
            float lx = (xl >= W - 1) ? 0.0f : (xc - (float)xl);
            float hy = 1.0f - ly, hx = 1.0f - lx;
            int rl = min(max(yl - row_lo, 0), rows - 1);
            int rh = min(max(yh - row_lo, 0), rows - 1);
            int cl = min(max(xl - col_lo, 0), cols - 1);
            int ch = min(max(xh - col_lo, 0), cols - 1);
            float vs = valid ? 0.25f : 0.0f;
            soff[s][0] = rl * cols + cl;  swt[s][0] = hy * hx * vs;
            soff[s][1] = rl * cols + ch;  swt[s][1] = hy * lx * vs;
            soff[s][2] = rh * cols + cl;  swt[s][2] = ly * hx * vs;
            soff[s][3] = rh * cols + ch;  swt[s][3] = ly * lx * vs;
        }
    }

    const size_t HW = (size_t)(H * W);
    const float* bbase = f + (size_t)b * NUM_CH * HW;
    const size_t roff  = (size_t)row_lo * W + col_lo;
    const int c0 = g * GRP;

    for (int chunk = 0; chunk < NCHUNK; ++chunk) {
        const int cbase = c0 + chunk * CB;

        // ---- stage CB channel rects, coalesced row-major ----
        const float* pl0 = bbase + (size_t)cbase * HW + roff;
        for (int j = tid; j < F; j += 256) {
            int r = (int)((float)j * rcp_cols);
            int c = j - r * cols;
            if (c < 0)          { r -= 1; c += cols; }
            else if (c >= cols) { r += 1; c -= cols; }
            const float* src = pl0 + (size_t)r * W + c;
            #pragma unroll
            for (int ci2 = 0; ci2 < CB; ++ci2)        // 4 independent loads
                lds[ci2 * MAXE + j] = src[ci2 * HW];
        }
        __syncthreads();

        // ---- compute 196 outputs from LDS ----
        if (active) {
            const float* Lb = &lds[ci * MAXE];
            float acc = 0.0f;
            #pragma unroll
            for (int s = 0; s < 4; ++s)
                acc += swt[s][0] * Lb[soff[s][0]] + swt[s][1] * Lb[soff[s][1]]
                     + swt[s][2] * Lb[soff[s][2]] + swt[s][3] * Lb[soff[s][3]];
            out[((size_t)k * NUM_CH + cbase + ci) * 49 + p] = acc;
        }
        if (chunk != NCHUNK - 1) __syncthreads();
    }
}

extern "C" void kernel_launch(void* const* d_in, const int* in_sizes, int n_in,
                              void* d_out, int out_size, void* d_ws, size_t ws_size,
                              hipStream_t stream) {
    const float* f0   = (const float*)d_in[0];
    const float* f1   = (const float*)d_in[1];
    const float* f2   = (const float*)d_in[2];
    const float* f3   = (const float*)d_in[3];
    const float* rois = (const float*)d_in[4];
    // d_in[5] = rois_counts (unused)
    const int* level = (const int*)d_in[6];
    float* out = (float*)d_out;

    int K = out_size / (NUM_CH * 49);          // 512
    int blocks = K * (NUM_CH / GRP);           // K * 16 = 8192
    roi_align_lds_kernel<<<blocks, 256, 0, stream>>>(f0, f1, f2, f3, rois, level, out);
}

// Round 7
// 186.930 us; speedup vs baseline: 1.3234x; 1.3234x over previous
//
#include <hip/hip_runtime.h>

// ROI Align (FPN, PH=PW=7, SR=2), fp32 I/O (verified R4).
// R7: R4 structure (best so far) + paired-x gathers.
// Model: kernel is L1 address/transaction bound (R4/R5/R6 all consistent).
// The x-corner pair (xl, xl+1) is contiguous -> one dwordx2 load replaces
// two dword gathers: halves gather instructions AND distinct-line lookups.
// Branch-free: weights pre-folded with (valid ? 0.25 : 0), indices clamped.

#define NUM_CH 256

typedef float floatx2 __attribute__((ext_vector_type(2)));

__global__ __launch_bounds__(256) void roi_align_kernel(
    const float* __restrict__ f0,
    const float* __restrict__ f1,
    const float* __restrict__ f2,
    const float* __restrict__ f3,
    const float* __restrict__ rois_f,
    const int* __restrict__ level,
    float* __restrict__ out,
    int total)
{
    int e = blockIdx.x * blockDim.x + threadIdx.x;
    if (e >= total) return;

    int p  = e % 49;           // output pixel (lane-minor)
    int t  = e / 49;
    int c  = t % NUM_CH;       // channel
    int k  = t / NUM_CH;       // roi
    int ph = p / 7;
    int pw = p % 7;

    int lvl = level[k];
    const float* f;
    int H, W; float scale;
    if (lvl == 0)      { f = f0; H = 200; W = 200; scale = 0.25f;    }
    else if (lvl == 1) { f = f1; H = 100; W = 100; scale = 0.125f;   }
    else if (lvl == 2) { f = f2; H = 50;  W = 50;  scale = 0.0625f;  }
    else               { f = f3; H = 25;  W = 25;  scale = 0.03125f; }

    const float* rf = rois_f + (size_t)k * 5;
    float r0 = rf[0];
    float x1 = rf[1] * scale, y1 = rf[2] * scale;
    float x2 = rf[3] * scale, y2 = rf[4] * scale;
    int b = (int)r0;
    b = (b < 0) ? 0 : ((b > 1) ? 1 : b);

    float bh = fmaxf(y2 - y1, 1.0f) * (1.0f / 7.0f);
    float bw = fmaxf(x2 - x1, 1.0f) * (1.0f / 7.0f);

    const float* base = f + ((size_t)b * NUM_CH + c) * (size_t)(H * W);

    // ---- geometry for all 4 subsamples (branch-free) ----------------------
    int   offA[4], offB[4];            // row offsets of the float2 pair loads
    float selhi[4];                    // 1.0 if xl was clamped to W-1
    float w00[4], w01[4], w10[4], w11[4];
    #pragma unroll
    for (int s = 0; s < 4; ++s) {
        int sy = s >> 1, sx = s & 1;
        float y = y1 + (float)ph * bh + ((float)sy + 0.5f) * (bh * 0.5f);
        float x = x1 + (float)pw * bw + ((float)sx + 0.5f) * (bw * 0.5f);
        bool valid = (y > -1.0f) && (y < (float)H) && (x > -1.0f) && (x < (float)W);
        float yc = fmaxf(y, 0.0f), xc = fmaxf(x, 0.0f);
        int yl = min((int)yc, H - 1);
        int yh = min(yl + 1, H - 1);
        int xl = min((int)xc, W - 1);
        float ly = (yl >= H - 1) ? 0.0f : (yc - (float)yl);
        float lx = (xl >= W - 1) ? 0.0f : (xc - (float)xl);
        float hy = 1.0f - ly, hx = 1.0f - lx;
        int xb = min(xl, W - 2);       // pair base; if clamped, lx==0 so w01 dead
        selhi[s] = (xl > xb) ? 1.0f : 0.0f;
        offA[s] = yl * W + xb;
        offB[s] = yh * W + xb;
        float vs = valid ? 0.25f : 0.0f;
        w00[s] = hy * hx * vs;
        w01[s] = hy * lx * vs;
        w10[s] = ly * hx * vs;
        w11[s] = ly * lx * vs;
    }

    // ---- 8 independent dwordx2 gathers ------------------------------------
    floatx2 va[4], vb[4];
    #pragma unroll
    for (int s = 0; s < 4; ++s) {
        va[s] = *(const floatx2*)(base + offA[s]);   // row yl: [xb, xb+1]
        vb[s] = *(const floatx2*)(base + offB[s]);   // row yh: [xb, xb+1]
    }

    float acc = 0.0f;
    #pragma unroll
    for (int s = 0; s < 4; ++s) {
        // v00/v10: if xl was clamped (selhi), the wanted value is lane .y
        float v00 = va[s].x + selhi[s] * (va[s].y - va[s].x);
        float v10 = vb[s].x + selhi[s] * (vb[s].y - vb[s].x);
        acc += w00[s] * v00 + w01[s] * va[s].y
             + w10[s] * v10 + w11[s] * vb[s].y;
    }

    out[e] = acc;
}

extern "C" void kernel_launch(void* const* d_in, const int* in_sizes, int n_in,
                              void* d_out, int out_size, void* d_ws, size_t ws_size,
                              hipStream_t stream) {
    const float* f0   = (const float*)d_in[0];
    const float* f1   = (const float*)d_in[1];
    const float* f2   = (const float*)d_in[2];
    const float* f3   = (const float*)d_in[3];
    const float* rois = (const float*)d_in[4];
    // d_in[5] = rois_counts (unused)
    const int* level = (const int*)d_in[6];
    float* out = (float*)d_out;

    int total = out_size;  // K * 256 * 49
    int threads = 256;
    int blocks = (total + threads - 1) / threads;
    roi_align_kernel<<<blocks, threads, 0, stream>>>(f0, f1, f2, f3, rois, level, out, total);
}